// Round 4
// baseline (118.673 us; speedup 1.0000x reference)
//
#include <hip/hip_runtime.h>

typedef __bf16 bf16;
typedef __bf16 bf16x8 __attribute__((ext_vector_type(8)));
typedef float f32x4 __attribute__((ext_vector_type(4)));

#define BS 64
#define CI 64
#define LEN 4096
#define CO 128
#define KS 7
#define NK 4
#define HID 16
#define TEMP 30.0f

#define KTOT 448            // CI*KS
#define WROW 456            // padded wagg row (elems)
#define WBAT (CO * WROW)    // 58368 elems per batch
#define XROW 72             // padded x-tile row (i dim); 144B
#define XC 134              // l-window 128 + 6 halo
#define LTILE 128

// ---------------- pool: mean over L ----------------
__global__ void pool_kernel(const float* __restrict__ x, float* __restrict__ pooled) {
    int bc = blockIdx.x;
    const float4* xp = (const float4*)(x + (size_t)bc * LEN);
    int t = threadIdx.x;
    float s = 0.f;
#pragma unroll
    for (int j = 0; j < 4; ++j) {
        float4 v = xp[t + 256 * j];
        s += (v.x + v.y) + (v.z + v.w);
    }
#pragma unroll
    for (int off = 32; off > 0; off >>= 1) s += __shfl_down(s, off, 64);
    __shared__ float red[4];
    if ((t & 63) == 0) red[t >> 6] = s;
    __syncthreads();
    if (t == 0) pooled[bc] = (red[0] + red[1] + red[2] + red[3]) * (1.0f / LEN);
}

// ---------------- attention + weight aggregation (fused) ----------------
__global__ void attn_aggw_kernel(const float* __restrict__ pooled,
                                 const float* __restrict__ w1,
                                 const float* __restrict__ w2,
                                 const float* __restrict__ bias,
                                 const float* __restrict__ weight,
                                 float* __restrict__ aggb_g,
                                 bf16* __restrict__ wagg) {
    int b = blockIdx.x, t = threadIdx.x;
    __shared__ float p[CI], h[HID], att[NK];
    if (t < CI) p[t] = pooled[b * CI + t];
    __syncthreads();
    if (t < HID) {
        float s = 0.f;
        for (int i = 0; i < CI; ++i) s += p[i] * w1[t * CI + i];
        h[t] = fmaxf(s, 0.f);
    }
    __syncthreads();
    if (t == 0) {
        float lg[NK];
        float m = -1e30f;
        for (int k = 0; k < NK; ++k) {
            float s = 0.f;
            for (int j = 0; j < HID; ++j) s += h[j] * w2[k * HID + j];
            lg[k] = s * (1.0f / TEMP);
            m = fmaxf(m, lg[k]);
        }
        float e[NK], tot = 0.f;
        for (int k = 0; k < NK; ++k) { e[k] = expf(lg[k] - m); tot += e[k]; }
        float inv = 1.0f / tot;
        for (int k = 0; k < NK; ++k) att[k] = e[k] * inv;
    }
    __syncthreads();
    if (t < CO) {
        float s = 0.f;
        for (int k = 0; k < NK; ++k) s += att[k] * bias[k * CO + t];
        aggb_g[b * CO + t] = s;
    }
    float a0 = att[0], a1 = att[1], a2 = att[2], a3 = att[3];
    bf16* wb = wagg + (size_t)b * WBAT;
    const int KSTR = CO * CI * KS;   // 57344
    for (int m = t; m < KSTR; m += 256) {
        int o = m / KTOT;            // const divisors -> magic-mul
        int r = m - o * KTOT;
        int i = r / KS;
        int f = r - i * KS;
        float v = a0 * weight[m] + a1 * weight[m + KSTR] +
                  a2 * weight[m + 2 * KSTR] + a3 * weight[m + 3 * KSTR];
        wb[o * WROW + f * 64 + i] = (bf16)v;
    }
}

// ---------------- conv: implicit GEMM, W in registers, x in LDS ----------------
struct XStage { float4 m[8]; float e1, e2; };

__global__ __launch_bounds__(256, 2) void conv_kernel(
    const float* __restrict__ x,
    const bf16* __restrict__ wagg,
    const float* __restrict__ aggb,
    float* __restrict__ out) {
    __shared__ __align__(16) bf16 lds_x[XC * XROW];   // 19296 B only

    int nwg = gridDim.x;                               // 4096 (mult of 8)
    int bid = blockIdx.x;
    int logical = (bid & 7) * (nwg >> 3) + (bid >> 3); // XCD-chunked swizzle (T1)
    int b = logical >> 6;
    int lsp = (logical >> 1) & 31;
    int oh = logical & 1;

    int t = threadIdx.x;
    int lane = t & 63, wid = t >> 6;
    int ln = lane & 15, g = lane >> 4;
    int wm = wid >> 1, wn = wid & 1;                   // wave tile: 32 o x 64 l

    // ---- A-fragments (W) straight into registers: 28 x bf16x8 = 112 VGPR ----
    const bf16* wgb = wagg + (size_t)b * WBAT
                    + (size_t)(oh * 64 + wm * 32 + ln) * WROW + g * 8;
    bf16x8 av[2][14];
#pragma unroll
    for (int mf = 0; mf < 2; ++mf)
#pragma unroll
        for (int kk = 0; kk < 14; ++kk)
            av[mf][kk] = *(const bf16x8*)(wgb + mf * 16 * WROW + kk * 32);

    int l0 = lsp * LTILE;
    int si = t >> 2, sf = t & 3;
    const float* xb = x + (size_t)b * CI * LEN;

    // ---- x tile loads (issued while av loads are in flight) ----
    XStage s0;
#pragma unroll
    for (int j = 0; j < 8; ++j) {
        int c4 = sf + 4 * j;
        s0.m[j] = *(const float4*)(xb + (size_t)si * LEN + l0 + 4 * c4);
    }
    {
        int i1 = t / 6, s1 = t - i1 * 6;
        int c1 = (s1 < 3) ? s1 : (128 + s1);
        int gl1 = l0 - 3 + c1;
        s0.e1 = (gl1 >= 0 && gl1 < LEN) ? xb[(size_t)i1 * LEN + gl1] : 0.f;
        s0.e2 = 0.f;
        if (t < 128) {
            int e2 = 256 + t, i2 = e2 / 6, s2 = e2 - i2 * 6;
            int c2 = (s2 < 3) ? s2 : (128 + s2);
            int gl2 = l0 - 3 + c2;
            s0.e2 = (gl2 >= 0 && gl2 < LEN) ? xb[(size_t)i2 * LEN + gl2] : 0.f;
        }
    }

    // bias + output row offsets: o = oh*64 + wm*32 + mf*16 + g*4 + r
    float bias_r[2][4];
    int orow_off[2][4];
#pragma unroll
    for (int mf = 0; mf < 2; ++mf)
#pragma unroll
        for (int r = 0; r < 4; ++r) {
            int o = oh * 64 + wm * 32 + mf * 16 + g * 4 + r;
            bias_r[mf][r] = aggb[b * CO + o];
            orow_off[mf][r] = (b * CO + o) * LEN;
        }

    // ---- transpose-write x tile to LDS ----
#pragma unroll
    for (int j = 0; j < 8; ++j) {
        int c4 = sf + 4 * j;
#pragma unroll
        for (int dl = 0; dl < 4; ++dl) {
            float v = (&s0.m[j].x)[dl];
            lds_x[(4 * c4 + 3 + dl) * XROW + si] = (bf16)v;
        }
    }
    {
        int i1 = t / 6, s1 = t - i1 * 6;
        int c1 = (s1 < 3) ? s1 : (128 + s1);
        lds_x[c1 * XROW + i1] = (bf16)s0.e1;
        if (t < 128) {
            int e2 = 256 + t, i2 = e2 / 6, s2 = e2 - i2 * 6;
            int c2 = (s2 < 3) ? s2 : (128 + s2);
            lds_x[c2 * XROW + i2] = (bf16)s0.e2;
        }
    }
    __syncthreads();                                   // the only barrier

    // ---- K-loop: 4 ds_read_b128 : 8 MFMA per kk, A from registers ----
    f32x4 acc[2][4];
#pragma unroll
    for (int mf = 0; mf < 2; ++mf)
#pragma unroll
        for (int nf = 0; nf < 4; ++nf)
            acc[mf][nf] = (f32x4){0.f, 0.f, 0.f, 0.f};

    const bf16* bp = lds_x + (wn * 64 + ln) * XROW + g * 8;

#pragma unroll
    for (int kk = 0; kk < 14; ++kk) {
        int boff = (kk >> 1) * XROW + (kk & 1) * 32;   // f-shift rows, i-half cols
        bf16x8 bv[4];
#pragma unroll
        for (int nf = 0; nf < 4; ++nf)
            bv[nf] = *(const bf16x8*)(bp + nf * 16 * XROW + boff);
#pragma unroll
        for (int mf = 0; mf < 2; ++mf)
#pragma unroll
            for (int nf = 0; nf < 4; ++nf)
                acc[mf][nf] = __builtin_amdgcn_mfma_f32_16x16x32_bf16(
                    av[mf][kk], bv[nf], acc[mf][nf], 0, 0, 0);
    }

    // ---- store + bias ----
#pragma unroll
    for (int mf = 0; mf < 2; ++mf)
#pragma unroll
        for (int nf = 0; nf < 4; ++nf) {
            int l = l0 + wn * 64 + nf * 16 + ln;
#pragma unroll
            for (int r = 0; r < 4; ++r)
                out[(size_t)orow_off[mf][r] + l] = acc[mf][nf][r] + bias_r[mf][r];
        }
}

extern "C" void kernel_launch(void* const* d_in, const int* in_sizes, int n_in,
                              void* d_out, int out_size, void* d_ws, size_t ws_size,
                              hipStream_t stream) {
    const float* x  = (const float*)d_in[0];
    const float* w1 = (const float*)d_in[1];
    const float* w2 = (const float*)d_in[2];
    const float* wt = (const float*)d_in[3];
    const float* bs = (const float*)d_in[4];
    float* out = (float*)d_out;

    bf16* wagg = (bf16*)d_ws;
    float* pooled = (float*)((char*)d_ws + (size_t)BS * WBAT * 2);
    float* aggb   = pooled + BS * CI;

    pool_kernel<<<BS * CI, 256, 0, stream>>>(x, pooled);
    attn_aggw_kernel<<<BS, 256, 0, stream>>>(pooled, w1, w2, bs, wt, aggb, wagg);
    conv_kernel<<<BS * 64, 256, 0, stream>>>(x, wagg, aggb, out);
}

// Round 5
// 75.792 us; speedup vs baseline: 1.5658x; 1.5658x over previous
//
#include <hip/hip_runtime.h>

typedef __bf16 bf16;
typedef __bf16 bf16x8 __attribute__((ext_vector_type(8)));
typedef __bf16 bf16x2 __attribute__((ext_vector_type(2)));
typedef float f32x4 __attribute__((ext_vector_type(4)));

#define BS 64
#define CI 64
#define LEN 4096
#define CO 128
#define KS 7
#define NK 4
#define HID 16
#define TEMP 30.0f

#define KTOT 448            // CI*KS
#define WROW 456            // padded wagg row (elems)
#define WBAT (CO * WROW)    // 58368 elems per batch
#define XROW 72             // padded x-tile row (i dim); 144B
#define XC 134              // l-window 128 + 6 halo
#define LTILE 128

// ---------------- pool: mean over L ----------------
__global__ void pool_kernel(const float* __restrict__ x, float* __restrict__ pooled) {
    int bc = blockIdx.x;
    const float4* xp = (const float4*)(x + (size_t)bc * LEN);
    int t = threadIdx.x;
    float s = 0.f;
#pragma unroll
    for (int j = 0; j < 4; ++j) {
        float4 v = xp[t + 256 * j];
        s += (v.x + v.y) + (v.z + v.w);
    }
#pragma unroll
    for (int off = 32; off > 0; off >>= 1) s += __shfl_down(s, off, 64);
    __shared__ float red[4];
    if ((t & 63) == 0) red[t >> 6] = s;
    __syncthreads();
    if (t == 0) pooled[bc] = (red[0] + red[1] + red[2] + red[3]) * (1.0f / LEN);
}

// ---------------- attention (tiny): att + aggregated bias ----------------
__global__ void attn_kernel(const float* __restrict__ pooled,
                            const float* __restrict__ w1,
                            const float* __restrict__ w2,
                            const float* __restrict__ bias,
                            float* __restrict__ att_g,
                            float* __restrict__ aggb_g) {
    int b = blockIdx.x, t = threadIdx.x;
    __shared__ float p[CI], h[HID], att[NK];
    if (t < CI) p[t] = pooled[b * CI + t];
    __syncthreads();
    if (t < HID) {
        float s = 0.f;
        for (int i = 0; i < CI; ++i) s += p[i] * w1[t * CI + i];
        h[t] = fmaxf(s, 0.f);
    }
    __syncthreads();
    if (t == 0) {
        float lg[NK];
        float m = -1e30f;
        for (int k = 0; k < NK; ++k) {
            float s = 0.f;
            for (int j = 0; j < HID; ++j) s += h[j] * w2[k * HID + j];
            lg[k] = s * (1.0f / TEMP);
            m = fmaxf(m, lg[k]);
        }
        float e[NK], tot = 0.f;
        for (int k = 0; k < NK; ++k) { e[k] = expf(lg[k] - m); tot += e[k]; }
        float inv = 1.0f / tot;
        for (int k = 0; k < NK; ++k) { att[k] = e[k] * inv; att_g[b * NK + k] = att[k]; }
    }
    __syncthreads();
    if (t < CO) {
        float s = 0.f;
        for (int k = 0; k < NK; ++k) s += att[k] * bias[k * CO + t];
        aggb_g[b * CO + t] = s;
    }
}

// ---------------- weight aggregation, wide: 128 o x 2 b-halves ----------------
// each weight element read ~2x total; per-thread w in registers; b-loop inner
__global__ void aggw_kernel(const float* __restrict__ weight,
                            const float* __restrict__ att_g,
                            bf16* __restrict__ wagg) {
    int o = blockIdx.x >> 1;
    int bh = blockIdx.x & 1;
    int t = threadIdx.x;
    __shared__ float lw[4 * KTOT];            // [bank][i*7+f]
    __shared__ __align__(16) float attl[128]; // this half's 32 b x 4

    const float* wo = weight + o * KTOT;
    for (int idx = t; idx < 4 * KTOT; idx += 256) {
        int bank = idx / KTOT;
        int r = idx - bank * KTOT;
        lw[idx] = wo[(size_t)bank * (CO * KTOT) + r];
    }
    if (t < 128) attl[t] = att_g[bh * 128 + t];
    __syncthreads();

    if (t < 224) {                            // kout pair (2t, 2t+1), kout = f*64+i
        float w8[8];
#pragma unroll
        for (int j = 0; j < 2; ++j) {
            int kout = 2 * t + j;
            int i = kout & 63, f = kout >> 6;
#pragma unroll
            for (int bank = 0; bank < 4; ++bank)
                w8[j * 4 + bank] = lw[bank * KTOT + i * KS + f];
        }
        for (int bb = 0; bb < 32; ++bb) {
            int b = bh * 32 + bb;
            float4 a = *(const float4*)&attl[bb * 4];
            float v0 = a.x * w8[0] + a.y * w8[1] + a.z * w8[2] + a.w * w8[3];
            float v1 = a.x * w8[4] + a.y * w8[5] + a.z * w8[6] + a.w * w8[7];
            bf16x2 pk; pk[0] = (bf16)v0; pk[1] = (bf16)v1;
            *(bf16x2*)(wagg + (size_t)b * WBAT + o * WROW + 2 * t) = pk;
        }
    }
}

// ---------------- conv: implicit GEMM, W in registers, x in LDS ----------------
struct XStage { float4 m[8]; float e1, e2; };

__global__ __launch_bounds__(256, 2) void conv_kernel(
    const float* __restrict__ x,
    const bf16* __restrict__ wagg,
    const float* __restrict__ aggb,
    float* __restrict__ out) {
    __shared__ __align__(16) bf16 lds_x[XC * XROW];   // 19296 B only

    int nwg = gridDim.x;                               // 4096 (mult of 8)
    int bid = blockIdx.x;
    int logical = (bid & 7) * (nwg >> 3) + (bid >> 3); // XCD-chunked swizzle (T1)
    int b = logical >> 6;
    int lsp = (logical >> 1) & 31;
    int oh = logical & 1;

    int t = threadIdx.x;
    int lane = t & 63, wid = t >> 6;
    int ln = lane & 15, g = lane >> 4;
    int wm = wid >> 1, wn = wid & 1;                   // wave tile: 32 o x 64 l

    // ---- A-fragments (W) straight into registers: 28 x bf16x8 = 112 VGPR ----
    const bf16* wgb = wagg + (size_t)b * WBAT
                    + (size_t)(oh * 64 + wm * 32 + ln) * WROW + g * 8;
    bf16x8 av[2][14];
#pragma unroll
    for (int mf = 0; mf < 2; ++mf)
#pragma unroll
        for (int kk = 0; kk < 14; ++kk)
            av[mf][kk] = *(const bf16x8*)(wgb + mf * 16 * WROW + kk * 32);

    int l0 = lsp * LTILE;
    int si = t >> 2, sf = t & 3;
    const float* xb = x + (size_t)b * CI * LEN;

    // ---- x tile loads (issued while av loads are in flight) ----
    XStage s0;
#pragma unroll
    for (int j = 0; j < 8; ++j) {
        int c4 = sf + 4 * j;
        s0.m[j] = *(const float4*)(xb + (size_t)si * LEN + l0 + 4 * c4);
    }
    {
        int i1 = t / 6, s1 = t - i1 * 6;
        int c1 = (s1 < 3) ? s1 : (128 + s1);
        int gl1 = l0 - 3 + c1;
        s0.e1 = (gl1 >= 0 && gl1 < LEN) ? xb[(size_t)i1 * LEN + gl1] : 0.f;
        s0.e2 = 0.f;
        if (t < 128) {
            int e2 = 256 + t, i2 = e2 / 6, s2 = e2 - i2 * 6;
            int c2 = (s2 < 3) ? s2 : (128 + s2);
            int gl2 = l0 - 3 + c2;
            s0.e2 = (gl2 >= 0 && gl2 < LEN) ? xb[(size_t)i2 * LEN + gl2] : 0.f;
        }
    }

    // bias + output row offsets: o = oh*64 + wm*32 + mf*16 + g*4 + r
    float bias_r[2][4];
    int orow_off[2][4];
#pragma unroll
    for (int mf = 0; mf < 2; ++mf)
#pragma unroll
        for (int r = 0; r < 4; ++r) {
            int o = oh * 64 + wm * 32 + mf * 16 + g * 4 + r;
            bias_r[mf][r] = aggb[b * CO + o];
            orow_off[mf][r] = (b * CO + o) * LEN;
        }

    // ---- transpose-write x tile to LDS ----
#pragma unroll
    for (int j = 0; j < 8; ++j) {
        int c4 = sf + 4 * j;
#pragma unroll
        for (int dl = 0; dl < 4; ++dl) {
            float v = (&s0.m[j].x)[dl];
            lds_x[(4 * c4 + 3 + dl) * XROW + si] = (bf16)v;
        }
    }
    {
        int i1 = t / 6, s1 = t - i1 * 6;
        int c1 = (s1 < 3) ? s1 : (128 + s1);
        lds_x[c1 * XROW + i1] = (bf16)s0.e1;
        if (t < 128) {
            int e2 = 256 + t, i2 = e2 / 6, s2 = e2 - i2 * 6;
            int c2 = (s2 < 3) ? s2 : (128 + s2);
            lds_x[c2 * XROW + i2] = (bf16)s0.e2;
        }
    }
    __syncthreads();                                   // the only barrier

    // ---- K-loop: 4 ds_read_b128 : 8 MFMA per kk, A from registers ----
    f32x4 acc[2][4];
#pragma unroll
    for (int mf = 0; mf < 2; ++mf)
#pragma unroll
        for (int nf = 0; nf < 4; ++nf)
            acc[mf][nf] = (f32x4){0.f, 0.f, 0.f, 0.f};

    const bf16* bp = lds_x + (wn * 64 + ln) * XROW + g * 8;

#pragma unroll
    for (int kk = 0; kk < 14; ++kk) {
        int boff = (kk >> 1) * XROW + (kk & 1) * 32;   // f-shift rows, i-half cols
        bf16x8 bv[4];
#pragma unroll
        for (int nf = 0; nf < 4; ++nf)
            bv[nf] = *(const bf16x8*)(bp + nf * 16 * XROW + boff);
#pragma unroll
        for (int mf = 0; mf < 2; ++mf)
#pragma unroll
            for (int nf = 0; nf < 4; ++nf)
                acc[mf][nf] = __builtin_amdgcn_mfma_f32_16x16x32_bf16(
                    av[mf][kk], bv[nf], acc[mf][nf], 0, 0, 0);
    }

    // ---- store + bias ----
#pragma unroll
    for (int mf = 0; mf < 2; ++mf)
#pragma unroll
        for (int nf = 0; nf < 4; ++nf) {
            int l = l0 + wn * 64 + nf * 16 + ln;
#pragma unroll
            for (int r = 0; r < 4; ++r)
                out[(size_t)orow_off[mf][r] + l] = acc[mf][nf][r] + bias_r[mf][r];
        }
}

extern "C" void kernel_launch(void* const* d_in, const int* in_sizes, int n_in,
                              void* d_out, int out_size, void* d_ws, size_t ws_size,
                              hipStream_t stream) {
    const float* x  = (const float*)d_in[0];
    const float* w1 = (const float*)d_in[1];
    const float* w2 = (const float*)d_in[2];
    const float* wt = (const float*)d_in[3];
    const float* bs = (const float*)d_in[4];
    float* out = (float*)d_out;

    bf16* wagg = (bf16*)d_ws;                              // 7,471,104 B
    float* pooled = (float*)((char*)d_ws + (size_t)BS * WBAT * 2);
    float* att_g  = pooled + BS * CI;
    float* aggb   = att_g + BS * NK;

    pool_kernel<<<BS * CI, 256, 0, stream>>>(x, pooled);
    attn_kernel<<<BS, 256, 0, stream>>>(pooled, w1, w2, bs, att_g, aggb);
    aggw_kernel<<<CO * 2, 256, 0, stream>>>(wt, att_g, wagg);
    conv_kernel<<<BS * 64, 256, 0, stream>>>(x, wagg, aggb, out);
}

// Round 6
// 68.434 us; speedup vs baseline: 1.7341x; 1.1075x over previous
//
#include <hip/hip_runtime.h>

typedef __bf16 bf16;
typedef __bf16 bf16x8 __attribute__((ext_vector_type(8)));
typedef __bf16 bf16x2 __attribute__((ext_vector_type(2)));
typedef float f32x4 __attribute__((ext_vector_type(4)));

#define BS 64
#define CI 64
#define LEN 4096
#define CO 128
#define KS 7
#define NK 4
#define HID 16
#define TEMP 30.0f

#define KTOT 448            // CI*KS
#define WROW 456            // padded wagg row (elems)
#define WBAT (CO * WROW)    // 58368 elems per batch
#define XROW 72             // padded x-tile row (i dim); 144B
#define XC 134              // l-window 128 + 6 halo
#define LTILE 128
#define TPB 4               // L-tiles per block (512 l)
#define WST 68              // store-stage row stride (f32)

// ---------------- pool: mean over L ----------------
__global__ void pool_kernel(const float* __restrict__ x, float* __restrict__ pooled) {
    int bc = blockIdx.x;
    const float4* xp = (const float4*)(x + (size_t)bc * LEN);
    int t = threadIdx.x;
    float s = 0.f;
#pragma unroll
    for (int j = 0; j < 4; ++j) {
        float4 v = xp[t + 256 * j];
        s += (v.x + v.y) + (v.z + v.w);
    }
#pragma unroll
    for (int off = 32; off > 0; off >>= 1) s += __shfl_down(s, off, 64);
    __shared__ float red[4];
    if ((t & 63) == 0) red[t >> 6] = s;
    __syncthreads();
    if (t == 0) pooled[bc] = (red[0] + red[1] + red[2] + red[3]) * (1.0f / LEN);
}

// ---------------- attention (tiny): att + aggregated bias ----------------
__global__ void attn_kernel(const float* __restrict__ pooled,
                            const float* __restrict__ w1,
                            const float* __restrict__ w2,
                            const float* __restrict__ bias,
                            float* __restrict__ att_g,
                            float* __restrict__ aggb_g) {
    int b = blockIdx.x, t = threadIdx.x;
    __shared__ float p[CI], h[HID], att[NK];
    if (t < CI) p[t] = pooled[b * CI + t];
    __syncthreads();
    if (t < HID) {
        float s = 0.f;
        for (int i = 0; i < CI; ++i) s += p[i] * w1[t * CI + i];
        h[t] = fmaxf(s, 0.f);
    }
    __syncthreads();
    if (t == 0) {
        float lg[NK];
        float m = -1e30f;
        for (int k = 0; k < NK; ++k) {
            float s = 0.f;
            for (int j = 0; j < HID; ++j) s += h[j] * w2[k * HID + j];
            lg[k] = s * (1.0f / TEMP);
            m = fmaxf(m, lg[k]);
        }
        float e[NK], tot = 0.f;
        for (int k = 0; k < NK; ++k) { e[k] = expf(lg[k] - m); tot += e[k]; }
        float inv = 1.0f / tot;
        for (int k = 0; k < NK; ++k) { att[k] = e[k] * inv; att_g[b * NK + k] = att[k]; }
    }
    __syncthreads();
    if (t < CO) {
        float s = 0.f;
        for (int k = 0; k < NK; ++k) s += att[k] * bias[k * CO + t];
        aggb_g[b * CO + t] = s;
    }
}

// ---------------- weight aggregation, wide: 128 o x 2 b-halves ----------------
__global__ void aggw_kernel(const float* __restrict__ weight,
                            const float* __restrict__ att_g,
                            bf16* __restrict__ wagg) {
    int o = blockIdx.x >> 1;
    int bh = blockIdx.x & 1;
    int t = threadIdx.x;
    __shared__ float lw[4 * KTOT];            // [bank][i*7+f]
    __shared__ __align__(16) float attl[128]; // this half's 32 b x 4

    const float* wo = weight + o * KTOT;
    for (int idx = t; idx < 4 * KTOT; idx += 256) {
        int bank = idx / KTOT;
        int r = idx - bank * KTOT;
        lw[idx] = wo[(size_t)bank * (CO * KTOT) + r];
    }
    if (t < 128) attl[t] = att_g[bh * 128 + t];
    __syncthreads();

    if (t < 224) {                            // kout pair (2t, 2t+1), kout = f*64+i
        float w8[8];
#pragma unroll
        for (int j = 0; j < 2; ++j) {
            int kout = 2 * t + j;
            int i = kout & 63, f = kout >> 6;
#pragma unroll
            for (int bank = 0; bank < 4; ++bank)
                w8[j * 4 + bank] = lw[bank * KTOT + i * KS + f];
        }
        for (int bb = 0; bb < 32; ++bb) {
            int b = bh * 32 + bb;
            float4 a = *(const float4*)&attl[bb * 4];
            float v0 = a.x * w8[0] + a.y * w8[1] + a.z * w8[2] + a.w * w8[3];
            float v1 = a.x * w8[4] + a.y * w8[5] + a.z * w8[6] + a.w * w8[7];
            bf16x2 pk; pk[0] = (bf16)v0; pk[1] = (bf16)v1;
            *(bf16x2*)(wagg + (size_t)b * WBAT + o * WROW + 2 * t) = pk;
        }
    }
}

// ---------------- conv: implicit GEMM, W in regs, 4 L-tiles/block ----------------
struct XStage { float4 m[8]; float e1, e2; };

__global__ __launch_bounds__(256, 2) void conv_kernel(
    const float* __restrict__ x,
    const bf16* __restrict__ wagg,
    const float* __restrict__ aggb,
    float* __restrict__ out) {
    __shared__ __align__(16) bf16 lds_x[2][XC * XROW];   // 2 x 19296 B
    __shared__ __align__(16) float lds_st[4][32 * WST];  // 4 x 8704 B  (total 73408 B)

    int nwg = gridDim.x;                               // 1024 (mult of 8)
    int bid = blockIdx.x;
    int logical = (bid & 7) * (nwg >> 3) + (bid >> 3); // XCD-chunked swizzle (T1)
    int b = logical >> 4;
    int rem = logical & 15;
    int oh = rem >> 3, lsp = rem & 7;

    int t = threadIdx.x;
    int lane = t & 63, wid = t >> 6;
    int ln = lane & 15, g = lane >> 4;
    int wm = wid >> 1, wn = wid & 1;                   // wave tile: 32 o x 64 l

    // ---- A-fragments (W) into registers, once per 512 l ----
    const bf16* wgb = wagg + (size_t)b * WBAT
                    + (size_t)(oh * 64 + wm * 32 + ln) * WROW + g * 8;
    bf16x8 av[2][14];
#pragma unroll
    for (int mf = 0; mf < 2; ++mf)
#pragma unroll
        for (int kk = 0; kk < 14; ++kk)
            av[mf][kk] = *(const bf16x8*)(wgb + mf * 16 * WROW + kk * 32);

    int l0base = lsp * (LTILE * TPB);
    int si = t >> 2, sf = t & 3;
    const float* xb = x + (size_t)b * CI * LEN;

    auto load_x = [&](int l0, XStage& s) {
#pragma unroll
        for (int j = 0; j < 8; ++j) {
            int c4 = sf + 4 * j;
            s.m[j] = *(const float4*)(xb + (size_t)si * LEN + l0 + 4 * c4);
        }
        int i1 = t / 6, s1 = t - i1 * 6;
        int c1 = (s1 < 3) ? s1 : (128 + s1);
        int gl1 = l0 - 3 + c1;
        s.e1 = (gl1 >= 0 && gl1 < LEN) ? xb[(size_t)i1 * LEN + gl1] : 0.f;
        s.e2 = 0.f;
        if (t < 128) {
            int e2 = 256 + t, i2 = e2 / 6, s2 = e2 - i2 * 6;
            int c2 = (s2 < 3) ? s2 : (128 + s2);
            int gl2 = l0 - 3 + c2;
            s.e2 = (gl2 >= 0 && gl2 < LEN) ? xb[(size_t)i2 * LEN + gl2] : 0.f;
        }
    };
    auto write_x = [&](int buf, const XStage& s) {
        bf16* lb = lds_x[buf];
#pragma unroll
        for (int j = 0; j < 8; ++j) {
            int c4 = sf + 4 * j;
#pragma unroll
            for (int dl = 0; dl < 4; ++dl) {
                float v = (&s.m[j].x)[dl];
                lb[(4 * c4 + 3 + dl) * XROW + si] = (bf16)v;
            }
        }
        int i1 = t / 6, s1 = t - i1 * 6;
        int c1 = (s1 < 3) ? s1 : (128 + s1);
        lb[c1 * XROW + i1] = (bf16)s.e1;
        if (t < 128) {
            int e2 = 256 + t, i2 = e2 / 6, s2 = e2 - i2 * 6;
            int c2 = (s2 < 3) ? s2 : (128 + s2);
            lb[c2 * XROW + i2] = (bf16)s.e2;
        }
    };

    // bias: o = oh*64 + wm*32 + mf*16 + g*4 + r
    float bias_r[2][4];
#pragma unroll
    for (int mf = 0; mf < 2; ++mf)
#pragma unroll
        for (int r = 0; r < 4; ++r)
            bias_r[mf][r] = aggb[b * CO + oh * 64 + wm * 32 + mf * 16 + g * 4 + r];

    XStage s0;
    load_x(l0base, s0);
    write_x(0, s0);
    __syncthreads();

    float* st = &lds_st[wid][0];
    size_t orow0 = ((size_t)(b * CO + oh * 64 + wm * 32)) * LEN;

    for (int tl = 0; tl < TPB; ++tl) {
        int l0 = l0base + tl * LTILE;
        XStage sn;
        if (tl + 1 < TPB) load_x(l0 + LTILE, sn);   // issue early (T14)

        f32x4 acc[2][4];
#pragma unroll
        for (int mf = 0; mf < 2; ++mf)
#pragma unroll
            for (int nf = 0; nf < 4; ++nf)
                acc[mf][nf] = (f32x4){0.f, 0.f, 0.f, 0.f};

        const bf16* bp = lds_x[tl & 1] + (wn * 64 + ln) * XROW + g * 8;

#pragma unroll
        for (int kk = 0; kk < 14; ++kk) {
            int boff = (kk >> 1) * XROW + (kk & 1) * 32;   // f-shift rows, i-half cols
            bf16x8 bv[4];
#pragma unroll
            for (int nf = 0; nf < 4; ++nf)
                bv[nf] = *(const bf16x8*)(bp + nf * 16 * XROW + boff);
#pragma unroll
            for (int mf = 0; mf < 2; ++mf)
#pragma unroll
                for (int nf = 0; nf < 4; ++nf)
                    acc[mf][nf] = __builtin_amdgcn_mfma_f32_16x16x32_bf16(
                        av[mf][kk], bv[nf], acc[mf][nf], 0, 0, 0);
        }

        // ---- store via wave-private LDS stage: coalesced dwordx4 ----
#pragma unroll
        for (int mf = 0; mf < 2; ++mf)
#pragma unroll
            for (int nf = 0; nf < 4; ++nf)
#pragma unroll
                for (int r = 0; r < 4; ++r)
                    st[(mf * 16 + g * 4 + r) * WST + nf * 16 + ln] =
                        acc[mf][nf][r] + bias_r[mf][r];
        asm volatile("s_waitcnt lgkmcnt(0)" ::: "memory");
        __builtin_amdgcn_sched_barrier(0);
#pragma unroll
        for (int s = 0; s < 8; ++s) {
            int rl = s * 4 + g;
            f32x4 v = *(const f32x4*)(st + rl * WST + 4 * ln);
            *(f32x4*)(out + orow0 + (size_t)rl * LEN + l0 + wn * 64 + 4 * ln) = v;
        }

        if (tl + 1 < TPB) write_x((tl + 1) & 1, sn);   // other buffer: safe pre-barrier
        if (tl + 1 < TPB) __syncthreads();
    }
}

extern "C" void kernel_launch(void* const* d_in, const int* in_sizes, int n_in,
                              void* d_out, int out_size, void* d_ws, size_t ws_size,
                              hipStream_t stream) {
    const float* x  = (const float*)d_in[0];
    const float* w1 = (const float*)d_in[1];
    const float* w2 = (const float*)d_in[2];
    const float* wt = (const float*)d_in[3];
    const float* bs = (const float*)d_in[4];
    float* out = (float*)d_out;

    bf16* wagg = (bf16*)d_ws;                              // 7,471,104 B
    float* pooled = (float*)((char*)d_ws + (size_t)BS * WBAT * 2);
    float* att_g  = pooled + BS * CI;
    float* aggb   = att_g + BS * NK;

    pool_kernel<<<BS * CI, 256, 0, stream>>>(x, pooled);
    attn_kernel<<<BS, 256, 0, stream>>>(pooled, w1, w2, bs, att_g, aggb);
    aggw_kernel<<<CO * 2, 256, 0, stream>>>(wt, att_g, wagg);
    conv_kernel<<<BS * 16, 256, 0, stream>>>(x, wagg, aggb, out);
}

// Round 7
// 64.986 us; speedup vs baseline: 1.8261x; 1.0531x over previous
//
#include <hip/hip_runtime.h>

typedef __bf16 bf16;
typedef __bf16 bf16x8 __attribute__((ext_vector_type(8)));
typedef __bf16 bf16x2 __attribute__((ext_vector_type(2)));
typedef float f32x4 __attribute__((ext_vector_type(4)));

#define BS 64
#define CI 64
#define LEN 4096
#define CO 128
#define KS 7
#define NK 4
#define HID 16
#define TEMP 30.0f

#define KTOT 448            // CI*KS
#define WROW 456            // padded wagg row (elems)
#define WBAT (CO * WROW)    // 58368 elems per batch
#define XROW 72             // padded x-tile row (i dim); 144B
#define XC 134              // l-window 128 + 6 halo
#define LTILE 128
#define TPB 8               // L-tiles per block (1024 l)

// ---------------- pool: mean over L ----------------
__global__ void pool_kernel(const float* __restrict__ x, float* __restrict__ pooled) {
    int bc = blockIdx.x;
    const float4* xp = (const float4*)(x + (size_t)bc * LEN);
    int t = threadIdx.x;
    float s = 0.f;
#pragma unroll
    for (int j = 0; j < 4; ++j) {
        float4 v = xp[t + 256 * j];
        s += (v.x + v.y) + (v.z + v.w);
    }
#pragma unroll
    for (int off = 32; off > 0; off >>= 1) s += __shfl_down(s, off, 64);
    __shared__ float red[4];
    if ((t & 63) == 0) red[t >> 6] = s;
    __syncthreads();
    if (t == 0) pooled[bc] = (red[0] + red[1] + red[2] + red[3]) * (1.0f / LEN);
}

// ---------------- attention (tiny): att + aggregated bias ----------------
__global__ void attn_kernel(const float* __restrict__ pooled,
                            const float* __restrict__ w1,
                            const float* __restrict__ w2,
                            const float* __restrict__ bias,
                            float* __restrict__ att_g,
                            float* __restrict__ aggb_g) {
    int b = blockIdx.x, t = threadIdx.x;
    __shared__ float p[CI], h[HID], att[NK];
    if (t < CI) p[t] = pooled[b * CI + t];
    __syncthreads();
    if (t < HID) {
        float s = 0.f;
        for (int i = 0; i < CI; ++i) s += p[i] * w1[t * CI + i];
        h[t] = fmaxf(s, 0.f);
    }
    __syncthreads();
    if (t == 0) {
        float lg[NK];
        float m = -1e30f;
        for (int k = 0; k < NK; ++k) {
            float s = 0.f;
            for (int j = 0; j < HID; ++j) s += h[j] * w2[k * HID + j];
            lg[k] = s * (1.0f / TEMP);
            m = fmaxf(m, lg[k]);
        }
        float e[NK], tot = 0.f;
        for (int k = 0; k < NK; ++k) { e[k] = expf(lg[k] - m); tot += e[k]; }
        float inv = 1.0f / tot;
        for (int k = 0; k < NK; ++k) { att[k] = e[k] * inv; att_g[b * NK + k] = att[k]; }
    }
    __syncthreads();
    if (t < CO) {
        float s = 0.f;
        for (int k = 0; k < NK; ++k) s += att[k] * bias[k * CO + t];
        aggb_g[b * CO + t] = s;
    }
}

// ---------------- weight aggregation, wide: 128 o x 2 b-halves ----------------
__global__ void aggw_kernel(const float* __restrict__ weight,
                            const float* __restrict__ att_g,
                            bf16* __restrict__ wagg) {
    int o = blockIdx.x >> 1;
    int bh = blockIdx.x & 1;
    int t = threadIdx.x;
    __shared__ float lw[4 * KTOT];            // [bank][i*7+f]
    __shared__ __align__(16) float attl[128]; // this half's 32 b x 4

    const float* wo = weight + o * KTOT;
    for (int idx = t; idx < 4 * KTOT; idx += 256) {
        int bank = idx / KTOT;
        int r = idx - bank * KTOT;
        lw[idx] = wo[(size_t)bank * (CO * KTOT) + r];
    }
    if (t < 128) attl[t] = att_g[bh * 128 + t];
    __syncthreads();

    if (t < 224) {                            // kout pair (2t, 2t+1), kout = f*64+i
        float w8[8];
#pragma unroll
        for (int j = 0; j < 2; ++j) {
            int kout = 2 * t + j;
            int i = kout & 63, f = kout >> 6;
#pragma unroll
            for (int bank = 0; bank < 4; ++bank)
                w8[j * 4 + bank] = lw[bank * KTOT + i * KS + f];
        }
        for (int bb = 0; bb < 32; ++bb) {
            int b = bh * 32 + bb;
            float4 a = *(const float4*)&attl[bb * 4];
            float v0 = a.x * w8[0] + a.y * w8[1] + a.z * w8[2] + a.w * w8[3];
            float v1 = a.x * w8[4] + a.y * w8[5] + a.z * w8[6] + a.w * w8[7];
            bf16x2 pk; pk[0] = (bf16)v0; pk[1] = (bf16)v1;
            *(bf16x2*)(wagg + (size_t)b * WBAT + o * WROW + 2 * t) = pk;
        }
    }
}

// ---------------- conv: implicit GEMM, W in regs, 8 L-tiles/block ----------------
struct XStage { float4 m[8]; float e1, e2; };

__global__ __launch_bounds__(256, 2) void conv_kernel(
    const float* __restrict__ x,
    const bf16* __restrict__ wagg,
    const float* __restrict__ aggb,
    float* __restrict__ out) {
    __shared__ __align__(16) bf16 lds_x[2][XC * XROW];   // 2 x 19296 B = 38592 B

    int nwg = gridDim.x;                               // 512 (mult of 8)
    int bid = blockIdx.x;
    int logical = (bid & 7) * (nwg >> 3) + (bid >> 3); // XCD-chunked swizzle (T1)
    int b = logical >> 3;
    int rem = logical & 7;
    int oh = rem >> 2, lsp = rem & 3;

    int t = threadIdx.x;
    int lane = t & 63, wid = t >> 6;
    int ln = lane & 15, g = lane >> 4;
    int wm = wid >> 1, wn = wid & 1;                   // wave tile: 32 o x 64 l

    // ---- A-fragments (W) into registers, once per 1024 l ----
    const bf16* wgb = wagg + (size_t)b * WBAT
                    + (size_t)(oh * 64 + wm * 32 + ln) * WROW + g * 8;
    bf16x8 av[2][14];
#pragma unroll
    for (int mf = 0; mf < 2; ++mf)
#pragma unroll
        for (int kk = 0; kk < 14; ++kk)
            av[mf][kk] = *(const bf16x8*)(wgb + mf * 16 * WROW + kk * 32);

    int l0base = lsp * (LTILE * TPB);
    int si = t >> 2, sf = t & 3;
    const float* xb = x + (size_t)b * CI * LEN;

    auto load_x = [&](int l0, XStage& s) {
#pragma unroll
        for (int j = 0; j < 8; ++j) {
            int c4 = sf + 4 * j;
            s.m[j] = *(const float4*)(xb + (size_t)si * LEN + l0 + 4 * c4);
        }
        int i1 = t / 6, s1 = t - i1 * 6;
        int c1 = (s1 < 3) ? s1 : (128 + s1);
        int gl1 = l0 - 3 + c1;
        s.e1 = (gl1 >= 0 && gl1 < LEN) ? xb[(size_t)i1 * LEN + gl1] : 0.f;
        s.e2 = 0.f;
        if (t < 128) {
            int e2 = 256 + t, i2 = e2 / 6, s2 = e2 - i2 * 6;
            int c2 = (s2 < 3) ? s2 : (128 + s2);
            int gl2 = l0 - 3 + c2;
            s.e2 = (gl2 >= 0 && gl2 < LEN) ? xb[(size_t)i2 * LEN + gl2] : 0.f;
        }
    };
    auto write_x = [&](int buf, const XStage& s) {
        bf16* lb = lds_x[buf];
#pragma unroll
        for (int j = 0; j < 8; ++j) {
            int c4 = sf + 4 * j;
#pragma unroll
            for (int dl = 0; dl < 4; ++dl) {
                float v = (&s.m[j].x)[dl];
                lb[(4 * c4 + 3 + dl) * XROW + si] = (bf16)v;
            }
        }
        int i1 = t / 6, s1 = t - i1 * 6;
        int c1 = (s1 < 3) ? s1 : (128 + s1);
        lb[c1 * XROW + i1] = (bf16)s.e1;
        if (t < 128) {
            int e2 = 256 + t, i2 = e2 / 6, s2 = e2 - i2 * 6;
            int c2 = (s2 < 3) ? s2 : (128 + s2);
            lb[c2 * XROW + i2] = (bf16)s.e2;
        }
    };

    // bias + output row offsets: o = oh*64 + wm*32 + mf*16 + g*4 + r
    float bias_r[2][4];
    int orow_off[2][4];
#pragma unroll
    for (int mf = 0; mf < 2; ++mf)
#pragma unroll
        for (int r = 0; r < 4; ++r) {
            int o = oh * 64 + wm * 32 + mf * 16 + g * 4 + r;
            bias_r[mf][r] = aggb[b * CO + o];
            orow_off[mf][r] = (b * CO + o) * LEN;
        }

    XStage s0;
    load_x(l0base, s0);
    write_x(0, s0);
    __syncthreads();

    for (int tl = 0; tl < TPB; ++tl) {
        int l0 = l0base + tl * LTILE;
        XStage sn;
        if (tl + 1 < TPB) load_x(l0 + LTILE, sn);   // issue early (T14)

        f32x4 acc[2][4];
#pragma unroll
        for (int mf = 0; mf < 2; ++mf)
#pragma unroll
            for (int nf = 0; nf < 4; ++nf)
                acc[mf][nf] = (f32x4){0.f, 0.f, 0.f, 0.f};

        const bf16* bp = lds_x[tl & 1] + (wn * 64 + ln) * XROW + g * 8;

#pragma unroll
        for (int kk = 0; kk < 14; ++kk) {
            int boff = (kk >> 1) * XROW + (kk & 1) * 32;   // f-shift rows, i-half cols
            bf16x8 bv[4];
#pragma unroll
            for (int nf = 0; nf < 4; ++nf)
                bv[nf] = *(const bf16x8*)(bp + nf * 16 * XROW + boff);
#pragma unroll
            for (int mf = 0; mf < 2; ++mf)
#pragma unroll
                for (int nf = 0; nf < 4; ++nf)
                    acc[mf][nf] = __builtin_amdgcn_mfma_f32_16x16x32_bf16(
                        av[mf][kk], bv[nf], acc[mf][nf], 0, 0, 0);
        }

        // ---- direct store + bias (16-lane x 4B = full 64B lines) ----
#pragma unroll
        for (int mf = 0; mf < 2; ++mf)
#pragma unroll
            for (int nf = 0; nf < 4; ++nf) {
                int l = l0 + wn * 64 + nf * 16 + ln;
#pragma unroll
                for (int r = 0; r < 4; ++r)
                    out[(size_t)orow_off[mf][r] + l] = acc[mf][nf][r] + bias_r[mf][r];
            }

        if (tl + 1 < TPB) {
            write_x((tl + 1) & 1, sn);   // other buffer: safe pre-barrier
            __syncthreads();
        }
    }
}

extern "C" void kernel_launch(void* const* d_in, const int* in_sizes, int n_in,
                              void* d_out, int out_size, void* d_ws, size_t ws_size,
                              hipStream_t stream) {
    const float* x  = (const float*)d_in[0];
    const float* w1 = (const float*)d_in[1];
    const float* w2 = (const float*)d_in[2];
    const float* wt = (const float*)d_in[3];
    const float* bs = (const float*)d_in[4];
    float* out = (float*)d_out;

    bf16* wagg = (bf16*)d_ws;                              // 7,471,104 B
    float* pooled = (float*)((char*)d_ws + (size_t)BS * WBAT * 2);
    float* att_g  = pooled + BS * CI;
    float* aggb   = att_g + BS * NK;

    pool_kernel<<<BS * CI, 256, 0, stream>>>(x, pooled);
    attn_kernel<<<BS, 256, 0, stream>>>(pooled, w1, w2, bs, att_g, aggb);
    aggw_kernel<<<CO * 2, 256, 0, stream>>>(wt, att_g, wagg);
    conv_kernel<<<BS * 8, 256, 0, stream>>>(x, wagg, aggb, out);
}